// Round 5
// baseline (996.372 us; speedup 1.0000x reference)
//
#include <hip/hip_runtime.h>

// Problem constants (match reference)
#define ED    32      // embedding / hidden dim
#define SEQ_T 200     // history length
#define NB    4096    // batch
#define H3    96      // 3*ED
#define IV    100001
#define PV    100001
#define DV    1001
#define PV_MAX 100000 // PV-1
#define TCHUNK 8      // time-steps per weight-reload chunk (short live ranges!)

__device__ __forceinline__ float rcp_fast(float x) { return __builtin_amdgcn_rcpf(x); }
__device__ __forceinline__ float sigmoid_fast(float x) { return rcp_fast(1.0f + __expf(-x)); }
__device__ __forceinline__ float tanh_fast(float x) {
  const float e = __expf(-2.0f * x);
  return (1.0f - e) * rcp_fast(1.0f + e);
}

// Broadcast lane K (0..31) within each 32-lane group via ds_swizzle BitMode:
// offset = (xor<<10)|(or<<5)|and ; and=0, or=K -> every lane reads lane K of its group.
#define BCAST(v, K) \
  __uint_as_float((unsigned)__builtin_amdgcn_ds_swizzle((int)__float_as_uint(v), ((K) << 5)))

#define UNROLL32(M) \
  M(0)  M(1)  M(2)  M(3)  M(4)  M(5)  M(6)  M(7)  \
  M(8)  M(9)  M(10) M(11) M(12) M(13) M(14) M(15) \
  M(16) M(17) M(18) M(19) M(20) M(21) M(22) M(23) \
  M(24) M(25) M(26) M(27) M(28) M(29) M(30) M(31)

template <int TOWER>
__device__ __forceinline__ void fetch_idx(const int* __restrict__ ids,
                                          const float* __restrict__ prices,
                                          const int* __restrict__ depts,
                                          int base, int t, float pmean, float prsq,
                                          int& idx, bool& mk) {
  if constexpr (TOWER == 0) {
    idx = ids[base + t];
    mk = true;
  } else if constexpr (TOWER == 1) {
    const float p = prices[base + t];
    const float pn = (p - pmean) * prsq;
    mk = (pn != 0.0f);
    int q = (int)pn;                       // trunc toward zero, like astype(int32)
    q = q < 0 ? 0 : (q > PV_MAX ? PV_MAX : q);
    idx = q;
  } else {
    const int d = depts[base + t];
    mk = (d != 0);
    idx = d;
  }
}

// ---------------------------------------------------------------------------
// Phase 1: XP[v][c] = table[v] @ Wx  — ROW PER LANE, weights streamed via
// scalar loads (wave-uniform addresses -> s_load, zero per-lane weight regs).
// Each lane: x[32] in VGPRs, 3 col-chunks of acc[32], 3072 v_fmac w/ SGPR src.
// ---------------------------------------------------------------------------
__global__ void __launch_bounds__(256, 2) proj_rpl(
    const float* __restrict__ table, const float* __restrict__ Wx,
    float* __restrict__ XP, int nrows) {
  const int r   = blockIdx.x * 256 + threadIdx.x;
  const bool on = r < nrows;
  const int rc  = on ? r : (nrows - 1);

  // Load this row's embedding (32 floats, 8 x float4 per lane).
  float x[ED];
  const float4* xr = (const float4*)(table + (size_t)rc * ED);
#pragma unroll
  for (int i = 0; i < 8; ++i) {
    const float4 v = xr[i];
    x[4 * i + 0] = v.x; x[4 * i + 1] = v.y; x[4 * i + 2] = v.z; x[4 * i + 3] = v.w;
  }

  float* o = XP + (size_t)rc * H3;
#pragma unroll
  for (int c = 0; c < 3; ++c) {
    float acc[32];
#pragma unroll
    for (int i = 0; i < 32; ++i) acc[i] = 0.0f;
#pragma unroll
    for (int k = 0; k < ED; ++k) {
      const float xk = x[k];
      const float* wrow = Wx + k * H3 + c * 32;   // wave-uniform -> scalar loads
#pragma unroll
      for (int i = 0; i < 32; ++i) acc[i] = __builtin_fmaf(xk, wrow[i], acc[i]);
    }
    if (on) {
      float4* ov = (float4*)(o + c * 32);
#pragma unroll
      for (int i = 0; i < 8; ++i)
        ov[i] = make_float4(acc[4 * i], acc[4 * i + 1], acc[4 * i + 2], acc[4 * i + 3]);
    }
  }
}

// ---------------------------------------------------------------------------
// Phase 2: GRU recurrence, 32 lanes per row (2 rows/wave), precomputed XP.
// Weights reloaded every TCHUNK steps: short live ranges the allocator keeps
// in arch VGPRs (round-1 evidence: in-loop loads got 124 VGPRs).
// The asm memory clobber blocks LICM from hoisting the reload out of the loop.
// ---------------------------------------------------------------------------
template <int TOWER>
__device__ void tower_c(const int* __restrict__ ids,
                        const float* __restrict__ prices,
                        const int* __restrict__ depts,
                        const float* __restrict__ XP,
                        const float* __restrict__ Wh,
                        const float* __restrict__ Bb,
                        float pmean, float prsq,
                        float* __restrict__ out) {
  const int j    = threadIdx.x & 31;                 // lane within row group = hidden col
  const int b    = blockIdx.x * 8 + (threadIdx.x >> 5);
  const int base = b * SEQ_T;

  const float bi0 = Bb[j],      bi1 = Bb[32 + j],  bi2 = Bb[64 + j];
  const float bh0 = Bb[96 + j], bh1 = Bb[128 + j], bh2 = Bb[160 + j];

  float h = 0.0f;

  // Prefetch xp for step 0.
  int idx; bool mk_next;
  fetch_idx<TOWER>(ids, prices, depts, base, 0, pmean, prsq, idx, mk_next);
  const float* xr = XP + (size_t)idx * H3 + j;
  float x0 = xr[0], x1 = xr[32], x2 = xr[64];

  float wh0[ED], wh1[ED], wh2[ED];

  for (int t0 = 0; t0 < SEQ_T; t0 += TCHUNK) {
    // Hard barrier for alias analysis: the weight loads below cannot be
    // hoisted above this (i.e., out of the t0 loop) -> live ranges span only
    // one chunk -> allocator keeps them in arch VGPRs.
    asm volatile("" ::: "memory");
#pragma unroll
    for (int k = 0; k < ED; ++k) {
      wh0[k] = Wh[k * H3 + j];
      wh1[k] = Wh[k * H3 + 32 + j];
      wh2[k] = Wh[k * H3 + 64 + j];
    }

#pragma unroll
    for (int dt = 0; dt < TCHUNK; ++dt) {
      const int t = t0 + dt;
      const float xv0 = x0, xv1 = x1, xv2 = x2;
      const bool  mk  = mk_next;
      if (t + 1 < SEQ_T) {
        int idn;
        fetch_idx<TOWER>(ids, prices, depts, base, t + 1, pmean, prsq, idn, mk_next);
        const float* xn = XP + (size_t)idn * H3 + j;
        x0 = xn[0]; x1 = xn[32]; x2 = xn[64];
      }

      float a0 = bi0 + xv0, a1 = bi1 + xv1, a2 = bi2 + xv2;  // x@Wx + bi
      float r0 = bh0, r1 = bh1, r2 = bh2;                    // h@Wh + bh

#define KSTEP(K)                              \
      {                                       \
        const float hk = BCAST(h, K);         \
        r0 = __builtin_fmaf(hk, wh0[K], r0);  \
        r1 = __builtin_fmaf(hk, wh1[K], r1);  \
        r2 = __builtin_fmaf(hk, wh2[K], r2);  \
      }
      UNROLL32(KSTEP)
#undef KSTEP

      const float z  = sigmoid_fast(a0 + r0);
      const float r  = sigmoid_fast(a1 + r1);
      const float hc = tanh_fast(a2 + r * r2);
      const float hn = z * h + (1.0f - z) * hc;
      h = mk ? hn : h;
    }
  }

  out[b * H3 + TOWER * ED + j] = h;
}

__global__ void __launch_bounds__(256, 2) gru_c(
    const int* __restrict__ ids, const float* __restrict__ prices, const int* __restrict__ depts,
    const float* __restrict__ itemXP, const float* __restrict__ priceXP,
    const float* __restrict__ deptXP,
    const float* __restrict__ item_Wh, const float* __restrict__ item_b,
    const float* __restrict__ price_Wh, const float* __restrict__ price_b,
    const float* __restrict__ dept_Wh, const float* __restrict__ dept_b,
    const float* __restrict__ price_mean, const float* __restrict__ price_var,
    float* __restrict__ out) {
  const int tower = blockIdx.y;
  if (tower == 0) {
    tower_c<0>(ids, prices, depts, itemXP, item_Wh, item_b, 0.0f, 0.0f, out);
  } else if (tower == 1) {
    const float pm = price_mean[0];
    const float pr = rsqrtf(price_var[0]);
    tower_c<1>(ids, prices, depts, priceXP, price_Wh, price_b, pm, pr, out);
  } else {
    tower_c<2>(ids, prices, depts, deptXP, dept_Wh, dept_b, 0.0f, 0.0f, out);
  }
}

// ---------------------------------------------------------------------------
// Fallback (ws too small): fused in-loop x@Wx (round-1 structure).
// ---------------------------------------------------------------------------
template <int TOWER>
__device__ void tower_run(const int* __restrict__ ids,
                          const float* __restrict__ prices,
                          const int* __restrict__ depts,
                          const float* __restrict__ table,
                          const float* __restrict__ Wx,
                          const float* __restrict__ Wh,
                          const float* __restrict__ Bb,
                          float pmean, float prsq,
                          float* __restrict__ out) {
  const int j    = threadIdx.x & 31;
  const int b    = blockIdx.x * 8 + (threadIdx.x >> 5);
  const int base = b * SEQ_T;

  float wx0[ED], wx1[ED], wx2[ED], wh0[ED], wh1[ED], wh2[ED];
#pragma unroll
  for (int k = 0; k < ED; ++k) {
    wx0[k] = Wx[k * H3 + j];
    wx1[k] = Wx[k * H3 + 32 + j];
    wx2[k] = Wx[k * H3 + 64 + j];
    wh0[k] = Wh[k * H3 + j];
    wh1[k] = Wh[k * H3 + 32 + j];
    wh2[k] = Wh[k * H3 + 64 + j];
  }
  const float bi0 = Bb[j],      bi1 = Bb[32 + j],  bi2 = Bb[64 + j];
  const float bh0 = Bb[96 + j], bh1 = Bb[128 + j], bh2 = Bb[160 + j];

  float h = 0.0f;
  int idx; bool mk_next;
  fetch_idx<TOWER>(ids, prices, depts, base, 0, pmean, prsq, idx, mk_next);
  float x_next = table[(size_t)idx * ED + j];

  for (int t = 0; t < SEQ_T; ++t) {
    const float xv = x_next;
    const bool  mk = mk_next;
    if (t + 1 < SEQ_T) {
      int idn;
      fetch_idx<TOWER>(ids, prices, depts, base, t + 1, pmean, prsq, idn, mk_next);
      x_next = table[(size_t)idn * ED + j];
    }

    float a0 = bi0, a1 = bi1, a2 = bi2;
    float r0 = bh0, r1 = bh1, r2 = bh2;
#define KSTEP(K)                              \
    {                                         \
      const float xk = BCAST(xv, K);          \
      const float hk = BCAST(h, K);           \
      a0 = __builtin_fmaf(xk, wx0[K], a0);    \
      a1 = __builtin_fmaf(xk, wx1[K], a1);    \
      a2 = __builtin_fmaf(xk, wx2[K], a2);    \
      r0 = __builtin_fmaf(hk, wh0[K], r0);    \
      r1 = __builtin_fmaf(hk, wh1[K], r1);    \
      r2 = __builtin_fmaf(hk, wh2[K], r2);    \
    }
    UNROLL32(KSTEP)
#undef KSTEP

    const float z  = sigmoid_fast(a0 + r0);
    const float r  = sigmoid_fast(a1 + r1);
    const float hc = tanh_fast(a2 + r * r2);
    const float hn = z * h + (1.0f - z) * hc;
    h = mk ? hn : h;
  }
  out[b * H3 + TOWER * ED + j] = h;
}

__global__ void __launch_bounds__(256, 2) gru_towers(
    const int* __restrict__ ids, const float* __restrict__ prices, const int* __restrict__ depts,
    const float* __restrict__ item_table, const float* __restrict__ price_table,
    const float* __restrict__ dept_table,
    const float* __restrict__ item_Wx, const float* __restrict__ item_Wh,
    const float* __restrict__ item_b,
    const float* __restrict__ price_Wx, const float* __restrict__ price_Wh,
    const float* __restrict__ price_b,
    const float* __restrict__ dept_Wx, const float* __restrict__ dept_Wh,
    const float* __restrict__ dept_b,
    const float* __restrict__ price_mean, const float* __restrict__ price_var,
    float* __restrict__ out) {
  const int tower = blockIdx.y;
  if (tower == 0) {
    tower_run<0>(ids, prices, depts, item_table, item_Wx, item_Wh, item_b, 0.0f, 0.0f, out);
  } else if (tower == 1) {
    const float pm = price_mean[0];
    const float pr = rsqrtf(price_var[0]);
    tower_run<1>(ids, prices, depts, price_table, price_Wx, price_Wh, price_b, pm, pr, out);
  } else {
    tower_run<2>(ids, prices, depts, dept_table, dept_Wx, dept_Wh, dept_b, 0.0f, 0.0f, out);
  }
}

extern "C" void kernel_launch(void* const* d_in, const int* in_sizes, int n_in,
                              void* d_out, int out_size, void* d_ws, size_t ws_size,
                              hipStream_t stream) {
  const int*   ids         = (const int*)d_in[0];
  const float* prices      = (const float*)d_in[1];
  const int*   depts       = (const int*)d_in[2];
  const float* item_table  = (const float*)d_in[3];
  const float* price_table = (const float*)d_in[4];
  const float* dept_table  = (const float*)d_in[5];
  const float* item_Wx     = (const float*)d_in[6];
  const float* item_Wh     = (const float*)d_in[7];
  const float* item_b      = (const float*)d_in[8];
  const float* price_Wx    = (const float*)d_in[9];
  const float* price_Wh    = (const float*)d_in[10];
  const float* price_b     = (const float*)d_in[11];
  const float* dept_Wx     = (const float*)d_in[12];
  const float* dept_Wh     = (const float*)d_in[13];
  const float* dept_b      = (const float*)d_in[14];
  const float* price_mean  = (const float*)d_in[15];
  const float* price_var   = (const float*)d_in[16];
  float* out = (float*)d_out;

  const size_t need = (size_t)(IV + PV + DV) * H3 * sizeof(float);
  if (ws_size >= need) {
    float* itemXP  = (float*)d_ws;
    float* priceXP = itemXP + (size_t)IV * H3;
    float* deptXP  = priceXP + (size_t)PV * H3;

    proj_rpl<<<dim3((IV + 255) / 256), 256, 0, stream>>>(item_table,  item_Wx,  itemXP,  IV);
    proj_rpl<<<dim3((PV + 255) / 256), 256, 0, stream>>>(price_table, price_Wx, priceXP, PV);
    proj_rpl<<<dim3((DV + 255) / 256), 256, 0, stream>>>(dept_table,  dept_Wx,  deptXP,  DV);

    dim3 grid(NB / 8, 3, 1);
    gru_c<<<grid, 256, 0, stream>>>(
        ids, prices, depts, itemXP, priceXP, deptXP,
        item_Wh, item_b, price_Wh, price_b, dept_Wh, dept_b,
        price_mean, price_var, out);
  } else {
    dim3 grid(NB / 8, 3, 1);
    gru_towers<<<grid, 256, 0, stream>>>(
        ids, prices, depts, item_table, price_table, dept_table,
        item_Wx, item_Wh, item_b, price_Wx, price_Wh, price_b,
        dept_Wx, dept_Wh, dept_b, price_mean, price_var, out);
  }
}

// Round 6
// 501.928 us; speedup vs baseline: 1.9851x; 1.9851x over previous
//
#include <hip/hip_runtime.h>

// Problem constants (match reference)
#define ED    32      // embedding / hidden dim
#define SEQ_T 200     // history length
#define NB    4096    // batch
#define H3    96      // 3*ED
#define IV    100001
#define PV    100001
#define DV    1001
#define PV_MAX 100000 // PV-1

// Pin a value into a VGPR at its definition point (round-3 proven variant).
#define PIN(x) asm volatile("" : "+v"(x))

__device__ __forceinline__ float rcp_fast(float x) { return __builtin_amdgcn_rcpf(x); }
__device__ __forceinline__ float sigmoid_fast(float x) { return rcp_fast(1.0f + __expf(-x)); }
__device__ __forceinline__ float tanh_fast(float x) {
  const float e = __expf(-2.0f * x);
  return (1.0f - e) * rcp_fast(1.0f + e);
}

// Broadcast lane K (0..31) within each 32-lane group via ds_swizzle BitMode:
// offset = (xor<<10)|(or<<5)|and ; and=0, or=K -> every lane reads lane K of its group.
#define BCAST(v, K) \
  __uint_as_float((unsigned)__builtin_amdgcn_ds_swizzle((int)__float_as_uint(v), ((K) << 5)))

#define UNROLL32(M) \
  M(0)  M(1)  M(2)  M(3)  M(4)  M(5)  M(6)  M(7)  \
  M(8)  M(9)  M(10) M(11) M(12) M(13) M(14) M(15) \
  M(16) M(17) M(18) M(19) M(20) M(21) M(22) M(23) \
  M(24) M(25) M(26) M(27) M(28) M(29) M(30) M(31)

template <int TOWER>
__device__ __forceinline__ void fetch_idx(const int* __restrict__ ids,
                                          const float* __restrict__ prices,
                                          const int* __restrict__ depts,
                                          int base, int t, float pmean, float prsq,
                                          int& idx, bool& mk) {
  if constexpr (TOWER == 0) {
    idx = ids[base + t];
    mk = true;
  } else if constexpr (TOWER == 1) {
    const float p = prices[base + t];
    const float pn = (p - pmean) * prsq;
    mk = (pn != 0.0f);
    int q = (int)pn;                       // trunc toward zero, like astype(int32)
    q = q < 0 ? 0 : (q > PV_MAX ? PV_MAX : q);
    idx = q;
  } else {
    const int d = depts[base + t];
    mk = (d != 0);
    idx = d;
  }
}

// ---------------------------------------------------------------------------
// Phase 1, fused: all three tables in ONE launch. Each 32-lane group loads
// its 96 weights once and projects 32 consecutive rows (8x better amortization
// than round 3's 4 rows/group). Output layout INTERLEAVED: XP[v*96 + j*3 + c]
// holds cols {j, 32+j, 64+j} so the GRU reads one 12-byte chunk per step.
// ---------------------------------------------------------------------------
#define NBLK_I ((IV + 255) / 256)
#define NBLK_P ((PV + 255) / 256)
#define NBLK_D ((DV + 255) / 256)

__global__ void __launch_bounds__(256, 2) proj_all(
    const float* __restrict__ item_table, const float* __restrict__ price_table,
    const float* __restrict__ dept_table,
    const float* __restrict__ item_Wx, const float* __restrict__ price_Wx,
    const float* __restrict__ dept_Wx,
    float* __restrict__ itemXP, float* __restrict__ priceXP,
    float* __restrict__ deptXP) {
  int blk = blockIdx.x;
  const float* table; const float* Wx; float* XP; int nrows;
  if (blk < NBLK_I)               { table = item_table;  Wx = item_Wx;  XP = itemXP;  nrows = IV; }
  else if (blk < NBLK_I + NBLK_P) { blk -= NBLK_I;       table = price_table; Wx = price_Wx; XP = priceXP; nrows = PV; }
  else                            { blk -= NBLK_I + NBLK_P; table = dept_table; Wx = dept_Wx; XP = deptXP; nrows = DV; }

  const int j = threadIdx.x & 31;
  const int g = threadIdx.x >> 5;

  float wx0[ED], wx1[ED], wx2[ED];
#pragma unroll
  for (int k = 0; k < ED; ++k) {
    wx0[k] = Wx[k * H3 + j];
    wx1[k] = Wx[k * H3 + 32 + j];
    wx2[k] = Wx[k * H3 + 64 + j];
    PIN(wx0[k]); PIN(wx1[k]); PIN(wx2[k]);
  }

  const int r0 = blk * 256 + g * 32;     // 32 rows per group
  for (int rr = 0; rr < 32; ++rr) {
    const int r = r0 + rr;
    if (r >= nrows) break;
    const float xv = table[(size_t)r * ED + j];   // coalesced 128B per row
    float a0 = 0.f, a1 = 0.f, a2 = 0.f;
#define PSTEP(K)                              \
    {                                         \
      const float xk = BCAST(xv, K);          \
      a0 = __builtin_fmaf(xk, wx0[K], a0);    \
      a1 = __builtin_fmaf(xk, wx1[K], a1);    \
      a2 = __builtin_fmaf(xk, wx2[K], a2);    \
    }
    UNROLL32(PSTEP)
#undef PSTEP
    float* o = XP + (size_t)r * H3 + j * 3;       // interleaved [v][j][3]
    o[0] = a0; o[1] = a1; o[2] = a2;              // merges to dwordx3
  }
}

// ---------------------------------------------------------------------------
// Phase 2: GRU recurrence (round-3 proven structure), 2 rows/wave.
// Per step: ONE 12B xp load + 32 h-broadcasts + 96 FMA + gates.
// ---------------------------------------------------------------------------
template <int TOWER>
__device__ void tower_pre(const int* __restrict__ ids,
                          const float* __restrict__ prices,
                          const int* __restrict__ depts,
                          const float* __restrict__ XP,
                          const float* __restrict__ Wh,
                          const float* __restrict__ Bb,
                          float pmean, float prsq,
                          float* __restrict__ out) {
  const int j    = threadIdx.x & 31;
  const int b    = blockIdx.x * 8 + (threadIdx.x >> 5);
  const int base = b * SEQ_T;

  float wh0[ED], wh1[ED], wh2[ED];
#pragma unroll
  for (int k = 0; k < ED; ++k) {
    wh0[k] = Wh[k * H3 + j];
    wh1[k] = Wh[k * H3 + 32 + j];
    wh2[k] = Wh[k * H3 + 64 + j];
    PIN(wh0[k]); PIN(wh1[k]); PIN(wh2[k]);
  }
  const float bi0 = Bb[j],      bi1 = Bb[32 + j],  bi2 = Bb[64 + j];
  const float bh0 = Bb[96 + j], bh1 = Bb[128 + j], bh2 = Bb[160 + j];

  float h = 0.0f;

  // Prefetch xp for step 0 (single 12B chunk).
  int idx; bool mk_next;
  fetch_idx<TOWER>(ids, prices, depts, base, 0, pmean, prsq, idx, mk_next);
  const float* xr = XP + (size_t)idx * H3 + j * 3;
  float x0 = xr[0], x1 = xr[1], x2 = xr[2];

  for (int t = 0; t < SEQ_T; ++t) {
    const float xv0 = x0, xv1 = x1, xv2 = x2;
    const bool  mk  = mk_next;
    if (t + 1 < SEQ_T) {
      int idn;
      fetch_idx<TOWER>(ids, prices, depts, base, t + 1, pmean, prsq, idn, mk_next);
      const float* xn = XP + (size_t)idn * H3 + j * 3;
      x0 = xn[0]; x1 = xn[1]; x2 = xn[2];
    }

    float a0 = bi0 + xv0, a1 = bi1 + xv1, a2 = bi2 + xv2;  // x@Wx + bi (precomputed)
    float r0 = bh0, r1 = bh1, r2 = bh2;                    // h@Wh + bh

#define KSTEP(K)                              \
    {                                         \
      const float hk = BCAST(h, K);           \
      r0 = __builtin_fmaf(hk, wh0[K], r0);    \
      r1 = __builtin_fmaf(hk, wh1[K], r1);    \
      r2 = __builtin_fmaf(hk, wh2[K], r2);    \
    }
    UNROLL32(KSTEP)
#undef KSTEP

    const float z  = sigmoid_fast(a0 + r0);
    const float r  = sigmoid_fast(a1 + r1);
    const float hc = tanh_fast(a2 + r * r2);
    const float hn = z * h + (1.0f - z) * hc;
    h = mk ? hn : h;
  }

  out[b * H3 + TOWER * ED + j] = h;
}

__global__ void __launch_bounds__(256, 2) gru_pre(
    const int* __restrict__ ids, const float* __restrict__ prices, const int* __restrict__ depts,
    const float* __restrict__ itemXP, const float* __restrict__ priceXP,
    const float* __restrict__ deptXP,
    const float* __restrict__ item_Wh, const float* __restrict__ item_b,
    const float* __restrict__ price_Wh, const float* __restrict__ price_b,
    const float* __restrict__ dept_Wh, const float* __restrict__ dept_b,
    const float* __restrict__ price_mean, const float* __restrict__ price_var,
    float* __restrict__ out) {
  const int tower = blockIdx.y;
  if (tower == 0) {
    tower_pre<0>(ids, prices, depts, itemXP, item_Wh, item_b, 0.0f, 0.0f, out);
  } else if (tower == 1) {
    const float pm = price_mean[0];
    const float pr = rsqrtf(price_var[0]);
    tower_pre<1>(ids, prices, depts, priceXP, price_Wh, price_b, pm, pr, out);
  } else {
    tower_pre<2>(ids, prices, depts, deptXP, dept_Wh, dept_b, 0.0f, 0.0f, out);
  }
}

// ---------------------------------------------------------------------------
// Fallback (ws too small): fused in-loop x@Wx (round-1 structure).
// ---------------------------------------------------------------------------
template <int TOWER>
__device__ void tower_run(const int* __restrict__ ids,
                          const float* __restrict__ prices,
                          const int* __restrict__ depts,
                          const float* __restrict__ table,
                          const float* __restrict__ Wx,
                          const float* __restrict__ Wh,
                          const float* __restrict__ Bb,
                          float pmean, float prsq,
                          float* __restrict__ out) {
  const int j    = threadIdx.x & 31;
  const int b    = blockIdx.x * 8 + (threadIdx.x >> 5);
  const int base = b * SEQ_T;

  float wx0[ED], wx1[ED], wx2[ED], wh0[ED], wh1[ED], wh2[ED];
#pragma unroll
  for (int k = 0; k < ED; ++k) {
    wx0[k] = Wx[k * H3 + j];
    wx1[k] = Wx[k * H3 + 32 + j];
    wx2[k] = Wx[k * H3 + 64 + j];
    wh0[k] = Wh[k * H3 + j];
    wh1[k] = Wh[k * H3 + 32 + j];
    wh2[k] = Wh[k * H3 + 64 + j];
  }
  const float bi0 = Bb[j],      bi1 = Bb[32 + j],  bi2 = Bb[64 + j];
  const float bh0 = Bb[96 + j], bh1 = Bb[128 + j], bh2 = Bb[160 + j];

  float h = 0.0f;
  int idx; bool mk_next;
  fetch_idx<TOWER>(ids, prices, depts, base, 0, pmean, prsq, idx, mk_next);
  float x_next = table[(size_t)idx * ED + j];

  for (int t = 0; t < SEQ_T; ++t) {
    const float xv = x_next;
    const bool  mk = mk_next;
    if (t + 1 < SEQ_T) {
      int idn;
      fetch_idx<TOWER>(ids, prices, depts, base, t + 1, pmean, prsq, idn, mk_next);
      x_next = table[(size_t)idn * ED + j];
    }

    float a0 = bi0, a1 = bi1, a2 = bi2;
    float r0 = bh0, r1 = bh1, r2 = bh2;
#define KSTEP(K)                              \
    {                                         \
      const float xk = BCAST(xv, K);          \
      const float hk = BCAST(h, K);           \
      a0 = __builtin_fmaf(xk, wx0[K], a0);    \
      a1 = __builtin_fmaf(xk, wx1[K], a1);    \
      a2 = __builtin_fmaf(xk, wx2[K], a2);    \
      r0 = __builtin_fmaf(hk, wh0[K], r0);    \
      r1 = __builtin_fmaf(hk, wh1[K], r1);    \
      r2 = __builtin_fmaf(hk, wh2[K], r2);    \
    }
    UNROLL32(KSTEP)
#undef KSTEP

    const float z  = sigmoid_fast(a0 + r0);
    const float r  = sigmoid_fast(a1 + r1);
    const float hc = tanh_fast(a2 + r * r2);
    const float hn = z * h + (1.0f - z) * hc;
    h = mk ? hn : h;
  }
  out[b * H3 + TOWER * ED + j] = h;
}

__global__ void __launch_bounds__(256, 2) gru_towers(
    const int* __restrict__ ids, const float* __restrict__ prices, const int* __restrict__ depts,
    const float* __restrict__ item_table, const float* __restrict__ price_table,
    const float* __restrict__ dept_table,
    const float* __restrict__ item_Wx, const float* __restrict__ item_Wh,
    const float* __restrict__ item_b,
    const float* __restrict__ price_Wx, const float* __restrict__ price_Wh,
    const float* __restrict__ price_b,
    const float* __restrict__ dept_Wx, const float* __restrict__ dept_Wh,
    const float* __restrict__ dept_b,
    const float* __restrict__ price_mean, const float* __restrict__ price_var,
    float* __restrict__ out) {
  const int tower = blockIdx.y;
  if (tower == 0) {
    tower_run<0>(ids, prices, depts, item_table, item_Wx, item_Wh, item_b, 0.0f, 0.0f, out);
  } else if (tower == 1) {
    const float pm = price_mean[0];
    const float pr = rsqrtf(price_var[0]);
    tower_run<1>(ids, prices, depts, price_table, price_Wx, price_Wh, price_b, pm, pr, out);
  } else {
    tower_run<2>(ids, prices, depts, dept_table, dept_Wx, dept_Wh, dept_b, 0.0f, 0.0f, out);
  }
}

extern "C" void kernel_launch(void* const* d_in, const int* in_sizes, int n_in,
                              void* d_out, int out_size, void* d_ws, size_t ws_size,
                              hipStream_t stream) {
  const int*   ids         = (const int*)d_in[0];
  const float* prices      = (const float*)d_in[1];
  const int*   depts       = (const int*)d_in[2];
  const float* item_table  = (const float*)d_in[3];
  const float* price_table = (const float*)d_in[4];
  const float* dept_table  = (const float*)d_in[5];
  const float* item_Wx     = (const float*)d_in[6];
  const float* item_Wh     = (const float*)d_in[7];
  const float* item_b      = (const float*)d_in[8];
  const float* price_Wx    = (const float*)d_in[9];
  const float* price_Wh    = (const float*)d_in[10];
  const float* price_b     = (const float*)d_in[11];
  const float* dept_Wx     = (const float*)d_in[12];
  const float* dept_Wh     = (const float*)d_in[13];
  const float* dept_b      = (const float*)d_in[14];
  const float* price_mean  = (const float*)d_in[15];
  const float* price_var   = (const float*)d_in[16];
  float* out = (float*)d_out;

  const size_t need = (size_t)(IV + PV + DV) * H3 * sizeof(float);
  if (ws_size >= need) {
    float* itemXP  = (float*)d_ws;
    float* priceXP = itemXP + (size_t)IV * H3;
    float* deptXP  = priceXP + (size_t)PV * H3;

    proj_all<<<dim3(NBLK_I + NBLK_P + NBLK_D), 256, 0, stream>>>(
        item_table, price_table, dept_table,
        item_Wx, price_Wx, dept_Wx,
        itemXP, priceXP, deptXP);

    dim3 grid(NB / 8, 3, 1);
    gru_pre<<<grid, 256, 0, stream>>>(
        ids, prices, depts, itemXP, priceXP, deptXP,
        item_Wh, item_b, price_Wh, price_b, dept_Wh, dept_b,
        price_mean, price_var, out);
  } else {
    dim3 grid(NB / 8, 3, 1);
    gru_towers<<<grid, 256, 0, stream>>>(
        ids, prices, depts, item_table, price_table, dept_table,
        item_Wx, item_Wh, item_b, price_Wx, price_Wh, price_b,
        dept_Wx, dept_Wh, dept_b, price_mean, price_var, out);
  }
}

// Round 7
// 464.928 us; speedup vs baseline: 2.1431x; 1.0796x over previous
//
#include <hip/hip_runtime.h>

// Problem constants (match reference)
#define ED    32      // embedding / hidden dim
#define SEQ_T 200     // history length
#define NB    4096    // batch
#define H3    96      // 3*ED
#define IV    100001
#define PV    100001
#define DV    1001
#define PV_MAX 100000 // PV-1

// Pin a value into a VGPR/AGPR at its definition point (keeps loads out of loop).
#define PIN(x) asm volatile("" : "+v"(x))

__device__ __forceinline__ float rcp_fast(float x) { return __builtin_amdgcn_rcpf(x); }
__device__ __forceinline__ float sigmoid_fast(float x) { return rcp_fast(1.0f + __expf(-x)); }
__device__ __forceinline__ float tanh_fast(float x) {
  const float e = __expf(-2.0f * x);
  return (1.0f - e) * rcp_fast(1.0f + e);
}

// Broadcast lane K (0..31) within each 32-lane group via ds_swizzle BitMode:
// offset = (xor<<10)|(or<<5)|and ; and=0, or=K -> every lane reads lane K of its group.
#define BCAST(v, K) \
  __uint_as_float((unsigned)__builtin_amdgcn_ds_swizzle((int)__float_as_uint(v), ((K) << 5)))

#define UNROLL32(M) \
  M(0)  M(1)  M(2)  M(3)  M(4)  M(5)  M(6)  M(7)  \
  M(8)  M(9)  M(10) M(11) M(12) M(13) M(14) M(15) \
  M(16) M(17) M(18) M(19) M(20) M(21) M(22) M(23) \
  M(24) M(25) M(26) M(27) M(28) M(29) M(30) M(31)

template <int TOWER>
__device__ __forceinline__ void fetch_idx(const int* __restrict__ ids,
                                          const float* __restrict__ prices,
                                          const int* __restrict__ depts,
                                          int base, int t, float pmean, float prsq,
                                          int& idx, bool& mk) {
  if constexpr (TOWER == 0) {
    idx = ids[base + t];
    mk = true;
  } else if constexpr (TOWER == 1) {
    const float p = prices[base + t];
    const float pn = (p - pmean) * prsq;
    mk = (pn != 0.0f);
    int q = (int)pn;                       // trunc toward zero, like astype(int32)
    q = q < 0 ? 0 : (q > PV_MAX ? PV_MAX : q);
    idx = q;
  } else {
    const int d = depts[base + t];
    mk = (d != 0);
    idx = d;
  }
}

// ---------------------------------------------------------------------------
// Phase 1, fused single launch, ROUND-3 XP LAYOUT: XP[v*96 + c] with lane j
// covering c = j, j+32, j+64 (stride-4 contiguous loads in the GRU — the
// interleaved layout of round 6 regressed: stride-12 component loads).
// 32 rows per 32-lane group amortizes the 96 weight loads.
// ---------------------------------------------------------------------------
#define NBLK_I ((IV + 255) / 256)
#define NBLK_P ((PV + 255) / 256)
#define NBLK_D ((DV + 255) / 256)

__global__ void __launch_bounds__(256, 2) proj_all(
    const float* __restrict__ item_table, const float* __restrict__ price_table,
    const float* __restrict__ dept_table,
    const float* __restrict__ item_Wx, const float* __restrict__ price_Wx,
    const float* __restrict__ dept_Wx,
    float* __restrict__ itemXP, float* __restrict__ priceXP,
    float* __restrict__ deptXP) {
  int blk = blockIdx.x;
  const float* table; const float* Wx; float* XP; int nrows;
  if (blk < NBLK_I)               { table = item_table;  Wx = item_Wx;  XP = itemXP;  nrows = IV; }
  else if (blk < NBLK_I + NBLK_P) { blk -= NBLK_I;       table = price_table; Wx = price_Wx; XP = priceXP; nrows = PV; }
  else                            { blk -= NBLK_I + NBLK_P; table = dept_table; Wx = dept_Wx; XP = deptXP; nrows = DV; }

  const int j = threadIdx.x & 31;
  const int g = threadIdx.x >> 5;

  float wx0[ED], wx1[ED], wx2[ED];
#pragma unroll
  for (int k = 0; k < ED; ++k) {
    wx0[k] = Wx[k * H3 + j];
    wx1[k] = Wx[k * H3 + 32 + j];
    wx2[k] = Wx[k * H3 + 64 + j];
    PIN(wx0[k]); PIN(wx1[k]); PIN(wx2[k]);
  }

  const int r0 = blk * 256 + g * 32;     // 32 rows per group
  for (int rr = 0; rr < 32; ++rr) {
    const int r = r0 + rr;
    if (r >= nrows) break;
    const float xv = table[(size_t)r * ED + j];   // coalesced 128B per row
    float a0 = 0.f, a1 = 0.f, a2 = 0.f;
#define PSTEP(K)                              \
    {                                         \
      const float xk = BCAST(xv, K);          \
      a0 = __builtin_fmaf(xk, wx0[K], a0);    \
      a1 = __builtin_fmaf(xk, wx1[K], a1);    \
      a2 = __builtin_fmaf(xk, wx2[K], a2);    \
    }
    UNROLL32(PSTEP)
#undef PSTEP
    float* o = XP + (size_t)r * H3;
    o[j] = a0; o[32 + j] = a1; o[64 + j] = a2;    // stride-4 coalesced
  }
}

// ---------------------------------------------------------------------------
// Phase 2: GRU recurrence, TWO ROWS PER LANE (4 rows/wave). Each weight value
// is fetched from the (AGPR-resident) array once per step and feeds 2 FMAs,
// halving the per-element accvgpr-copy bloat identified in rounds 3-6.
// ---------------------------------------------------------------------------
template <int TOWER>
__device__ void tower_pre2(const int* __restrict__ ids,
                           const float* __restrict__ prices,
                           const int* __restrict__ depts,
                           const float* __restrict__ XP,
                           const float* __restrict__ Wh,
                           const float* __restrict__ Bb,
                           float pmean, float prsq,
                           float* __restrict__ out) {
  const int j    = threadIdx.x & 31;
  const int g    = threadIdx.x >> 5;                 // group in block (0..7)
  const int bA   = blockIdx.x * 16 + g * 2;          // two rows per group
  const int bB   = bA + 1;
  const int baseA = bA * SEQ_T, baseB = bB * SEQ_T;

  float wh0[ED], wh1[ED], wh2[ED];
#pragma unroll
  for (int k = 0; k < ED; ++k) {
    wh0[k] = Wh[k * H3 + j];
    wh1[k] = Wh[k * H3 + 32 + j];
    wh2[k] = Wh[k * H3 + 64 + j];
    PIN(wh0[k]); PIN(wh1[k]); PIN(wh2[k]);
  }
  const float bi0 = Bb[j],      bi1 = Bb[32 + j],  bi2 = Bb[64 + j];
  const float bh0 = Bb[96 + j], bh1 = Bb[128 + j], bh2 = Bb[160 + j];

  float hA = 0.0f, hB = 0.0f;

  // Prefetch xp for step 0, both rows.
  int idxA, idxB; bool mkA_next, mkB_next;
  fetch_idx<TOWER>(ids, prices, depts, baseA, 0, pmean, prsq, idxA, mkA_next);
  fetch_idx<TOWER>(ids, prices, depts, baseB, 0, pmean, prsq, idxB, mkB_next);
  const float* xrA = XP + (size_t)idxA * H3 + j;
  const float* xrB = XP + (size_t)idxB * H3 + j;
  float xA0 = xrA[0], xA1 = xrA[32], xA2 = xrA[64];
  float xB0 = xrB[0], xB1 = xrB[32], xB2 = xrB[64];

  for (int t = 0; t < SEQ_T; ++t) {
    const float vA0 = xA0, vA1 = xA1, vA2 = xA2;
    const float vB0 = xB0, vB1 = xB1, vB2 = xB2;
    const bool  mkA = mkA_next, mkB = mkB_next;
    if (t + 1 < SEQ_T) {
      int inA, inB;
      fetch_idx<TOWER>(ids, prices, depts, baseA, t + 1, pmean, prsq, inA, mkA_next);
      fetch_idx<TOWER>(ids, prices, depts, baseB, t + 1, pmean, prsq, inB, mkB_next);
      const float* xnA = XP + (size_t)inA * H3 + j;
      const float* xnB = XP + (size_t)inB * H3 + j;
      xA0 = xnA[0]; xA1 = xnA[32]; xA2 = xnA[64];
      xB0 = xnB[0]; xB1 = xnB[32]; xB2 = xnB[64];
    }

    float rA0 = bh0, rA1 = bh1, rA2 = bh2;
    float rB0 = bh0, rB1 = bh1, rB2 = bh2;

#define KSTEP(K)                                 \
    {                                            \
      const float kA = BCAST(hA, K);             \
      const float kB = BCAST(hB, K);             \
      const float w0 = wh0[K], w1 = wh1[K], w2 = wh2[K]; \
      rA0 = __builtin_fmaf(kA, w0, rA0);         \
      rB0 = __builtin_fmaf(kB, w0, rB0);         \
      rA1 = __builtin_fmaf(kA, w1, rA1);         \
      rB1 = __builtin_fmaf(kB, w1, rB1);         \
      rA2 = __builtin_fmaf(kA, w2, rA2);         \
      rB2 = __builtin_fmaf(kB, w2, rB2);         \
    }
    UNROLL32(KSTEP)
#undef KSTEP

    {
      const float z  = sigmoid_fast(bi0 + vA0 + rA0);
      const float r  = sigmoid_fast(bi1 + vA1 + rA1);
      const float hc = tanh_fast(bi2 + vA2 + r * rA2);
      const float hn = z * hA + (1.0f - z) * hc;
      hA = mkA ? hn : hA;
    }
    {
      const float z  = sigmoid_fast(bi0 + vB0 + rB0);
      const float r  = sigmoid_fast(bi1 + vB1 + rB1);
      const float hc = tanh_fast(bi2 + vB2 + r * rB2);
      const float hn = z * hB + (1.0f - z) * hc;
      hB = mkB ? hn : hB;
    }
  }

  out[bA * H3 + TOWER * ED + j] = hA;
  out[bB * H3 + TOWER * ED + j] = hB;
}

__global__ void __launch_bounds__(256, 2) gru_pre2(
    const int* __restrict__ ids, const float* __restrict__ prices, const int* __restrict__ depts,
    const float* __restrict__ itemXP, const float* __restrict__ priceXP,
    const float* __restrict__ deptXP,
    const float* __restrict__ item_Wh, const float* __restrict__ item_b,
    const float* __restrict__ price_Wh, const float* __restrict__ price_b,
    const float* __restrict__ dept_Wh, const float* __restrict__ dept_b,
    const float* __restrict__ price_mean, const float* __restrict__ price_var,
    float* __restrict__ out) {
  const int tower = blockIdx.y;
  if (tower == 0) {
    tower_pre2<0>(ids, prices, depts, itemXP, item_Wh, item_b, 0.0f, 0.0f, out);
  } else if (tower == 1) {
    const float pm = price_mean[0];
    const float pr = rsqrtf(price_var[0]);
    tower_pre2<1>(ids, prices, depts, priceXP, price_Wh, price_b, pm, pr, out);
  } else {
    tower_pre2<2>(ids, prices, depts, deptXP, dept_Wh, dept_b, 0.0f, 0.0f, out);
  }
}

// ---------------------------------------------------------------------------
// Fallback (ws too small): fused in-loop x@Wx (round-1 structure).
// ---------------------------------------------------------------------------
template <int TOWER>
__device__ void tower_run(const int* __restrict__ ids,
                          const float* __restrict__ prices,
                          const int* __restrict__ depts,
                          const float* __restrict__ table,
                          const float* __restrict__ Wx,
                          const float* __restrict__ Wh,
                          const float* __restrict__ Bb,
                          float pmean, float prsq,
                          float* __restrict__ out) {
  const int j    = threadIdx.x & 31;
  const int b    = blockIdx.x * 8 + (threadIdx.x >> 5);
  const int base = b * SEQ_T;

  float wx0[ED], wx1[ED], wx2[ED], wh0[ED], wh1[ED], wh2[ED];
#pragma unroll
  for (int k = 0; k < ED; ++k) {
    wx0[k] = Wx[k * H3 + j];
    wx1[k] = Wx[k * H3 + 32 + j];
    wx2[k] = Wx[k * H3 + 64 + j];
    wh0[k] = Wh[k * H3 + j];
    wh1[k] = Wh[k * H3 + 32 + j];
    wh2[k] = Wh[k * H3 + 64 + j];
  }
  const float bi0 = Bb[j],      bi1 = Bb[32 + j],  bi2 = Bb[64 + j];
  const float bh0 = Bb[96 + j], bh1 = Bb[128 + j], bh2 = Bb[160 + j];

  float h = 0.0f;
  int idx; bool mk_next;
  fetch_idx<TOWER>(ids, prices, depts, base, 0, pmean, prsq, idx, mk_next);
  float x_next = table[(size_t)idx * ED + j];

  for (int t = 0; t < SEQ_T; ++t) {
    const float xv = x_next;
    const bool  mk = mk_next;
    if (t + 1 < SEQ_T) {
      int idn;
      fetch_idx<TOWER>(ids, prices, depts, base, t + 1, pmean, prsq, idn, mk_next);
      x_next = table[(size_t)idn * ED + j];
    }

    float a0 = bi0, a1 = bi1, a2 = bi2;
    float r0 = bh0, r1 = bh1, r2 = bh2;
#define KSTEP(K)                              \
    {                                         \
      const float xk = BCAST(xv, K);          \
      const float hk = BCAST(h, K);           \
      a0 = __builtin_fmaf(xk, wx0[K], a0);    \
      a1 = __builtin_fmaf(xk, wx1[K], a1);    \
      a2 = __builtin_fmaf(xk, wx2[K], a2);    \
      r0 = __builtin_fmaf(hk, wh0[K], r0);    \
      r1 = __builtin_fmaf(hk, wh1[K], r1);    \
      r2 = __builtin_fmaf(hk, wh2[K], r2);    \
    }
    UNROLL32(KSTEP)
#undef KSTEP

    const float z  = sigmoid_fast(a0 + r0);
    const float r  = sigmoid_fast(a1 + r1);
    const float hc = tanh_fast(a2 + r * r2);
    const float hn = z * h + (1.0f - z) * hc;
    h = mk ? hn : h;
  }
  out[b * H3 + TOWER * ED + j] = h;
}

__global__ void __launch_bounds__(256, 2) gru_towers(
    const int* __restrict__ ids, const float* __restrict__ prices, const int* __restrict__ depts,
    const float* __restrict__ item_table, const float* __restrict__ price_table,
    const float* __restrict__ dept_table,
    const float* __restrict__ item_Wx, const float* __restrict__ item_Wh,
    const float* __restrict__ item_b,
    const float* __restrict__ price_Wx, const float* __restrict__ price_Wh,
    const float* __restrict__ price_b,
    const float* __restrict__ dept_Wx, const float* __restrict__ dept_Wh,
    const float* __restrict__ dept_b,
    const float* __restrict__ price_mean, const float* __restrict__ price_var,
    float* __restrict__ out) {
  const int tower = blockIdx.y;
  if (tower == 0) {
    tower_run<0>(ids, prices, depts, item_table, item_Wx, item_Wh, item_b, 0.0f, 0.0f, out);
  } else if (tower == 1) {
    const float pm = price_mean[0];
    const float pr = rsqrtf(price_var[0]);
    tower_run<1>(ids, prices, depts, price_table, price_Wx, price_Wh, price_b, pm, pr, out);
  } else {
    tower_run<2>(ids, prices, depts, dept_table, dept_Wx, dept_Wh, dept_b, 0.0f, 0.0f, out);
  }
}

extern "C" void kernel_launch(void* const* d_in, const int* in_sizes, int n_in,
                              void* d_out, int out_size, void* d_ws, size_t ws_size,
                              hipStream_t stream) {
  const int*   ids         = (const int*)d_in[0];
  const float* prices      = (const float*)d_in[1];
  const int*   depts       = (const int*)d_in[2];
  const float* item_table  = (const float*)d_in[3];
  const float* price_table = (const float*)d_in[4];
  const float* dept_table  = (const float*)d_in[5];
  const float* item_Wx     = (const float*)d_in[6];
  const float* item_Wh     = (const float*)d_in[7];
  const float* item_b      = (const float*)d_in[8];
  const float* price_Wx    = (const float*)d_in[9];
  const float* price_Wh    = (const float*)d_in[10];
  const float* price_b     = (const float*)d_in[11];
  const float* dept_Wx     = (const float*)d_in[12];
  const float* dept_Wh     = (const float*)d_in[13];
  const float* dept_b      = (const float*)d_in[14];
  const float* price_mean  = (const float*)d_in[15];
  const float* price_var   = (const float*)d_in[16];
  float* out = (float*)d_out;

  const size_t need = (size_t)(IV + PV + DV) * H3 * sizeof(float);
  if (ws_size >= need) {
    float* itemXP  = (float*)d_ws;
    float* priceXP = itemXP + (size_t)IV * H3;
    float* deptXP  = priceXP + (size_t)PV * H3;

    proj_all<<<dim3(NBLK_I + NBLK_P + NBLK_D), 256, 0, stream>>>(
        item_table, price_table, dept_table,
        item_Wx, price_Wx, dept_Wx,
        itemXP, priceXP, deptXP);

    dim3 grid(NB / 16, 3, 1);   // 4 rows/wave (2 per lane)
    gru_pre2<<<grid, 256, 0, stream>>>(
        ids, prices, depts, itemXP, priceXP, deptXP,
        item_Wh, item_b, price_Wh, price_b, dept_Wh, dept_b,
        price_mean, price_var, out);
  } else {
    dim3 grid(NB / 8, 3, 1);
    gru_towers<<<grid, 256, 0, stream>>>(
        ids, prices, depts, item_table, price_table, dept_table,
        item_Wx, item_Wh, item_b, price_Wx, price_Wh, price_b,
        dept_Wx, dept_Wh, dept_b, price_mean, price_var, out);
  }
}

// Round 8
// 340.410 us; speedup vs baseline: 2.9270x; 1.3658x over previous
//
#include <hip/hip_runtime.h>

// Problem constants (match reference)
#define ED    32      // embedding / hidden dim
#define SEQ_T 200     // history length
#define NB    4096    // batch
#define H3    96      // 3*ED
#define IV    100001
#define PV    100001
#define DV    1001
#define PV_MAX 100000 // PV-1

#define PIN(x) asm volatile("" : "+v"(x))

typedef __attribute__((ext_vector_type(8))) short bf16x8;   // 8 bf16 (4 VGPRs)
typedef __attribute__((ext_vector_type(4))) float f32x4;    // MFMA acc

__device__ __forceinline__ float rcp_fast(float x) { return __builtin_amdgcn_rcpf(x); }
__device__ __forceinline__ float sigmoid_fast(float x) { return rcp_fast(1.0f + __expf(-x)); }
__device__ __forceinline__ float tanh_fast(float x) {
  const float e = __expf(-2.0f * x);
  return (1.0f - e) * rcp_fast(1.0f + e);
}

// round-to-nearest-even fp32 -> bf16 (as raw short)
__device__ __forceinline__ short bf16_rn(float v) {
  unsigned u = __float_as_uint(v);
  unsigned r = (u + 0x7fffu + ((u >> 16) & 1u)) >> 16;
  return (short)r;
}
__device__ __forceinline__ float bf16_f(short s) {
  return __uint_as_float(((unsigned)(unsigned short)s) << 16);
}

// Broadcast lane K within 32-lane group (swizzle-FMA kernels)
#define BCAST(v, K) \
  __uint_as_float((unsigned)__builtin_amdgcn_ds_swizzle((int)__float_as_uint(v), ((K) << 5)))

#define UNROLL32(M) \
  M(0)  M(1)  M(2)  M(3)  M(4)  M(5)  M(6)  M(7)  \
  M(8)  M(9)  M(10) M(11) M(12) M(13) M(14) M(15) \
  M(16) M(17) M(18) M(19) M(20) M(21) M(22) M(23) \
  M(24) M(25) M(26) M(27) M(28) M(29) M(30) M(31)

template <int TOWER>
__device__ __forceinline__ void fetch_idx(const int* __restrict__ ids,
                                          const float* __restrict__ prices,
                                          const int* __restrict__ depts,
                                          int base, int t, float pmean, float prsq,
                                          int& idx, bool& mk) {
  if constexpr (TOWER == 0) {
    idx = ids[base + t];
    mk = true;
  } else if constexpr (TOWER == 1) {
    const float p = prices[base + t];
    const float pn = (p - pmean) * prsq;
    mk = (pn != 0.0f);
    int q = (int)pn;
    q = q < 0 ? 0 : (q > PV_MAX ? PV_MAX : q);
    idx = q;
  } else {
    const int d = depts[base + t];
    mk = (d != 0);
    idx = d;
  }
}

// ---------------------------------------------------------------------------
// Phase 1 (unchanged from round 7): fused projection of all three tables.
// XP[v*96 + c], plain hidden order.
// ---------------------------------------------------------------------------
#define NBLK_I ((IV + 255) / 256)
#define NBLK_P ((PV + 255) / 256)
#define NBLK_D ((DV + 255) / 256)

__global__ void __launch_bounds__(256, 2) proj_all(
    const float* __restrict__ item_table, const float* __restrict__ price_table,
    const float* __restrict__ dept_table,
    const float* __restrict__ item_Wx, const float* __restrict__ price_Wx,
    const float* __restrict__ dept_Wx,
    float* __restrict__ itemXP, float* __restrict__ priceXP,
    float* __restrict__ deptXP) {
  int blk = blockIdx.x;
  const float* table; const float* Wx; float* XP; int nrows;
  if (blk < NBLK_I)               { table = item_table;  Wx = item_Wx;  XP = itemXP;  nrows = IV; }
  else if (blk < NBLK_I + NBLK_P) { blk -= NBLK_I;       table = price_table; Wx = price_Wx; XP = priceXP; nrows = PV; }
  else                            { blk -= NBLK_I + NBLK_P; table = dept_table; Wx = dept_Wx; XP = deptXP; nrows = DV; }

  const int j = threadIdx.x & 31;
  const int g = threadIdx.x >> 5;

  float wx0[ED], wx1[ED], wx2[ED];
#pragma unroll
  for (int k = 0; k < ED; ++k) {
    wx0[k] = Wx[k * H3 + j];
    wx1[k] = Wx[k * H3 + 32 + j];
    wx2[k] = Wx[k * H3 + 64 + j];
    PIN(wx0[k]); PIN(wx1[k]); PIN(wx2[k]);
  }

  const int r0 = blk * 256 + g * 32;
  for (int rr = 0; rr < 32; ++rr) {
    const int r = r0 + rr;
    if (r >= nrows) break;
    const float xv = table[(size_t)r * ED + j];
    float a0 = 0.f, a1 = 0.f, a2 = 0.f;
#define PSTEP(K)                              \
    {                                         \
      const float xk = BCAST(xv, K);          \
      a0 = __builtin_fmaf(xk, wx0[K], a0);    \
      a1 = __builtin_fmaf(xk, wx1[K], a1);    \
      a2 = __builtin_fmaf(xk, wx2[K], a2);    \
    }
    UNROLL32(PSTEP)
#undef PSTEP
    float* o = XP + (size_t)r * H3;
    o[j] = a0; o[32 + j] = a1; o[64 + j] = a2;
  }
}

// ---------------------------------------------------------------------------
// Phase 2: MFMA GRU. One wave = 16 batch rows. Per step:
//   rec^T[96x16] = Wh^T[96x32] @ h^T[32x16] via 6 tiles of
//   mfma_f32_16x16x32_bf16, split-bf16 (hi/lo) for fp32-like precision.
// A-frag (weights, loop-invariant): A[m=lane&15][k=quad*8+j] = Wh[k][16*tile+m]
// B-frag (state):                   B[k=quad*8+j][n=lane&15] = h[n][k]
// D (rec^T):                        D[m=quad*4+reg][n=lane&15]  (batch = lane&15)
// D->B transform for next step: in-wave LDS round trip (no barrier).
// ---------------------------------------------------------------------------
template <int TOWER>
__device__ void tower_mfma(const int* __restrict__ ids,
                           const float* __restrict__ prices,
                           const int* __restrict__ depts,
                           const float* __restrict__ XP,
                           const float* __restrict__ Wh,
                           const float* __restrict__ Bb,
                           float pmean, float prsq,
                           float* __restrict__ out,
                           float* __restrict__ smem) {
  const int lane = threadIdx.x & 63;
  const int l15  = lane & 15;
  const int quad = lane >> 4;
  const int wid  = threadIdx.x >> 6;
  const int grp  = blockIdx.x * 4 + wid;     // 16-row group
  const int bRow = grp * 16 + l15;           // this lane's batch row
  const int base = bRow * SEQ_T;
  float* my = smem + wid * 512;              // 16 rows x 32 cols fp32

  // Loop-invariant weight A-fragments (hi/lo split), 12 x bf16x8.
  bf16x8 wa_hi[6], wa_lo[6];
#pragma unroll
  for (int tile = 0; tile < 6; ++tile) {
#pragma unroll
    for (int j = 0; j < 8; ++j) {
      const float w = Wh[(quad * 8 + j) * H3 + tile * 16 + l15];
      const short hi = bf16_rn(w);
      const short lo = bf16_rn(w - bf16_f(hi));
      wa_hi[tile][j] = hi;
      wa_lo[tile][j] = lo;
    }
  }

  // Per-lane bias vectors in D-layout (hidden = tl*16 + quad*4 + reg).
  f32x4 cz[2], cr[2], bi2[2], bh2[2];
#pragma unroll
  for (int tl = 0; tl < 2; ++tl) {
    const int h4 = tl * 16 + quad * 4;
    cz[tl]  = *(const f32x4*)(Bb + h4)      + *(const f32x4*)(Bb + 96 + h4);
    cr[tl]  = *(const f32x4*)(Bb + 32 + h4) + *(const f32x4*)(Bb + 128 + h4);
    bi2[tl] = *(const f32x4*)(Bb + 64 + h4);
    bh2[tl] = *(const f32x4*)(Bb + 160 + h4);
  }

  f32x4 hD[2];                      // h in D-layout: hD[tl][reg] = h[batch=l15][hid=tl*16+quad*4+reg]
  hD[0] = (f32x4)0.0f; hD[1] = (f32x4)0.0f;

  // Prefetch xp for step 0 (6 float4 gathers in D-layout).
  int idx; bool mk_next;
  fetch_idx<TOWER>(ids, prices, depts, base, 0, pmean, prsq, idx, mk_next);
  f32x4 xq[6];
#pragma unroll
  for (int tile = 0; tile < 6; ++tile)
    xq[tile] = *(const f32x4*)(XP + (size_t)idx * H3 + tile * 16 + quad * 4);

  for (int t = 0; t < SEQ_T; ++t) {
    f32x4 xv[6];
#pragma unroll
    for (int tile = 0; tile < 6; ++tile) xv[tile] = xq[tile];
    const bool mk = mk_next;
    if (t + 1 < SEQ_T) {
      int idn;
      fetch_idx<TOWER>(ids, prices, depts, base, t + 1, pmean, prsq, idn, mk_next);
#pragma unroll
      for (int tile = 0; tile < 6; ++tile)
        xq[tile] = *(const f32x4*)(XP + (size_t)idn * H3 + tile * 16 + quad * 4);
    }

    // --- D-layout -> B-operand layout via in-wave LDS round trip ---
    *(f32x4*)(my + l15 * 32 + quad * 4)      = hD[0];
    *(f32x4*)(my + l15 * 32 + 16 + quad * 4) = hD[1];
    asm volatile("s_waitcnt lgkmcnt(0)" ::: "memory");
    const f32x4 b0 = *(const f32x4*)(my + l15 * 32 + quad * 8);
    const f32x4 b1 = *(const f32x4*)(my + l15 * 32 + quad * 8 + 4);

    bf16x8 hh, hl;
#pragma unroll
    for (int j = 0; j < 4; ++j) {
      short hi = bf16_rn(b0[j]);  hh[j] = hi;  hl[j] = bf16_rn(b0[j] - bf16_f(hi));
    }
#pragma unroll
    for (int j = 0; j < 4; ++j) {
      short hi = bf16_rn(b1[j]);  hh[4 + j] = hi;  hl[4 + j] = bf16_rn(b1[j] - bf16_f(hi));
    }

    // --- MFMA: acc = bias(+xp) + Wh^T @ h^T, split-bf16 (drop lo*lo) ---
    f32x4 acc[6];
    acc[0] = xv[0] + cz[0];  acc[1] = xv[1] + cz[1];
    acc[2] = xv[2] + cr[0];  acc[3] = xv[3] + cr[1];
    acc[4] = bh2[0];         acc[5] = bh2[1];
#pragma unroll
    for (int tile = 0; tile < 6; ++tile) {
      acc[tile] = __builtin_amdgcn_mfma_f32_16x16x32_bf16(wa_hi[tile], hh, acc[tile], 0, 0, 0);
      acc[tile] = __builtin_amdgcn_mfma_f32_16x16x32_bf16(wa_hi[tile], hl, acc[tile], 0, 0, 0);
      acc[tile] = __builtin_amdgcn_mfma_f32_16x16x32_bf16(wa_lo[tile], hh, acc[tile], 0, 0, 0);
    }

    // --- gates (all values for batch = l15, hidden = tl*16+quad*4+reg) ---
#pragma unroll
    for (int tl = 0; tl < 2; ++tl) {
#pragma unroll
      for (int rg = 0; rg < 4; ++rg) {
        const float z  = sigmoid_fast(acc[tl][rg]);
        const float r  = sigmoid_fast(acc[2 + tl][rg]);
        const float g  = tanh_fast(xv[4 + tl][rg] + bi2[tl][rg] + r * acc[4 + tl][rg]);
        const float hn = z * hD[tl][rg] + (1.0f - z) * g;
        hD[tl][rg] = mk ? hn : hD[tl][rg];
      }
    }
  }

  // Output: out[bRow][TOWER*32 + tl*16 + quad*4 + reg]
#pragma unroll
  for (int tl = 0; tl < 2; ++tl)
    *(f32x4*)(out + (size_t)bRow * H3 + TOWER * ED + tl * 16 + quad * 4) = hD[tl];
}

__global__ void __launch_bounds__(256) gru_mfma(
    const int* __restrict__ ids, const float* __restrict__ prices, const int* __restrict__ depts,
    const float* __restrict__ itemXP, const float* __restrict__ priceXP,
    const float* __restrict__ deptXP,
    const float* __restrict__ item_Wh, const float* __restrict__ item_b,
    const float* __restrict__ price_Wh, const float* __restrict__ price_b,
    const float* __restrict__ dept_Wh, const float* __restrict__ dept_b,
    const float* __restrict__ price_mean, const float* __restrict__ price_var,
    float* __restrict__ out) {
  __shared__ float smem[4 * 512];   // 2KB per wave
  const int tower = blockIdx.y;
  if (tower == 0) {
    tower_mfma<0>(ids, prices, depts, itemXP, item_Wh, item_b, 0.0f, 0.0f, out, smem);
  } else if (tower == 1) {
    const float pm = price_mean[0];
    const float pr = rsqrtf(price_var[0]);
    tower_mfma<1>(ids, prices, depts, priceXP, price_Wh, price_b, pm, pr, out, smem);
  } else {
    tower_mfma<2>(ids, prices, depts, deptXP, dept_Wh, dept_b, 0.0f, 0.0f, out, smem);
  }
}

// ---------------------------------------------------------------------------
// Fallback (ws too small): fused in-loop x@Wx (round-1 structure).
// ---------------------------------------------------------------------------
template <int TOWER>
__device__ void tower_run(const int* __restrict__ ids,
                          const float* __restrict__ prices,
                          const int* __restrict__ depts,
                          const float* __restrict__ table,
                          const float* __restrict__ Wx,
                          const float* __restrict__ Wh,
                          const float* __restrict__ Bb,
                          float pmean, float prsq,
                          float* __restrict__ out) {
  const int j    = threadIdx.x & 31;
  const int b    = blockIdx.x * 8 + (threadIdx.x >> 5);
  const int base = b * SEQ_T;

  float wx0[ED], wx1[ED], wx2[ED], wh0[ED], wh1[ED], wh2[ED];
#pragma unroll
  for (int k = 0; k < ED; ++k) {
    wx0[k] = Wx[k * H3 + j];
    wx1[k] = Wx[k * H3 + 32 + j];
    wx2[k] = Wx[k * H3 + 64 + j];
    wh0[k] = Wh[k * H3 + j];
    wh1[k] = Wh[k * H3 + 32 + j];
    wh2[k] = Wh[k * H3 + 64 + j];
  }
  const float bi0 = Bb[j],      bi1 = Bb[32 + j],  bi2 = Bb[64 + j];
  const float bh0 = Bb[96 + j], bh1 = Bb[128 + j], bh2 = Bb[160 + j];

  float h = 0.0f;
  int idx; bool mk_next;
  fetch_idx<TOWER>(ids, prices, depts, base, 0, pmean, prsq, idx, mk_next);
  float x_next = table[(size_t)idx * ED + j];

  for (int t = 0; t < SEQ_T; ++t) {
    const float xv = x_next;
    const bool  mk = mk_next;
    if (t + 1 < SEQ_T) {
      int idn;
      fetch_idx<TOWER>(ids, prices, depts, base, t + 1, pmean, prsq, idn, mk_next);
      x_next = table[(size_t)idn * ED + j];
    }

    float a0 = bi0, a1 = bi1, a2 = bi2;
    float r0 = bh0, r1 = bh1, r2 = bh2;
#define KSTEP(K)                              \
    {                                         \
      const float xk = BCAST(xv, K);          \
      const float hk = BCAST(h, K);           \
      a0 = __builtin_fmaf(xk, wx0[K], a0);    \
      a1 = __builtin_fmaf(xk, wx1[K], a1);    \
      a2 = __builtin_fmaf(xk, wx2[K], a2);    \
      r0 = __builtin_fmaf(hk, wh0[K], r0);    \
      r1 = __builtin_fmaf(hk, wh1[K], r1);    \
      r2 = __builtin_fmaf(hk, wh2[K], r2);    \
    }
    UNROLL32(KSTEP)
#undef KSTEP

    const float z  = sigmoid_fast(a0 + r0);
    const float r  = sigmoid_fast(a1 + r1);
    const float hc = tanh_fast(a2 + r * r2);
    const float hn = z * h + (1.0f - z) * hc;
    h = mk ? hn : h;
  }
  out[b * H3 + TOWER * ED + j] = h;
}

__global__ void __launch_bounds__(256, 2) gru_towers(
    const int* __restrict__ ids, const float* __restrict__ prices, const int* __restrict__ depts,
    const float* __restrict__ item_table, const float* __restrict__ price_table,
    const float* __restrict__ dept_table,
    const float* __restrict__ item_Wx, const float* __restrict__ item_Wh,
    const float* __restrict__ item_b,
    const float* __restrict__ price_Wx, const float* __restrict__ price_Wh,
    const float* __restrict__ price_b,
    const float* __restrict__ dept_Wx, const float* __restrict__ dept_Wh,
    const float* __restrict__ dept_b,
    const float* __restrict__ price_mean, const float* __restrict__ price_var,
    float* __restrict__ out) {
  const int tower = blockIdx.y;
  if (tower == 0) {
    tower_run<0>(ids, prices, depts, item_table, item_Wx, item_Wh, item_b, 0.0f, 0.0f, out);
  } else if (tower == 1) {
    const float pm = price_mean[0];
    const float pr = rsqrtf(price_var[0]);
    tower_run<1>(ids, prices, depts, price_table, price_Wx, price_Wh, price_b, pm, pr, out);
  } else {
    tower_run<2>(ids, prices, depts, dept_table, dept_Wx, dept_Wh, dept_b, 0.0f, 0.0f, out);
  }
}

extern "C" void kernel_launch(void* const* d_in, const int* in_sizes, int n_in,
                              void* d_out, int out_size, void* d_ws, size_t ws_size,
                              hipStream_t stream) {
  const int*   ids         = (const int*)d_in[0];
  const float* prices      = (const float*)d_in[1];
  const int*   depts       = (const int*)d_in[2];
  const float* item_table  = (const float*)d_in[3];
  const float* price_table = (const float*)d_in[4];
  const float* dept_table  = (const float*)d_in[5];
  const float* item_Wx     = (const float*)d_in[6];
  const float* item_Wh     = (const float*)d_in[7];
  const float* item_b      = (const float*)d_in[8];
  const float* price_Wx    = (const float*)d_in[9];
  const float* price_Wh    = (const float*)d_in[10];
  const float* price_b     = (const float*)d_in[11];
  const float* dept_Wx     = (const float*)d_in[12];
  const float* dept_Wh     = (const float*)d_in[13];
  const float* dept_b      = (const float*)d_in[14];
  const float* price_mean  = (const float*)d_in[15];
  const float* price_var   = (const float*)d_in[16];
  float* out = (float*)d_out;

  const size_t need = (size_t)(IV + PV + DV) * H3 * sizeof(float);
  if (ws_size >= need) {
    float* itemXP  = (float*)d_ws;
    float* priceXP = itemXP + (size_t)IV * H3;
    float* deptXP  = priceXP + (size_t)PV * H3;

    proj_all<<<dim3(NBLK_I + NBLK_P + NBLK_D), 256, 0, stream>>>(
        item_table, price_table, dept_table,
        item_Wx, price_Wx, dept_Wx,
        itemXP, priceXP, deptXP);

    dim3 grid(NB / 64, 3, 1);   // 4 x 16-row groups per block
    gru_mfma<<<grid, 256, 0, stream>>>(
        ids, prices, depts, itemXP, priceXP, deptXP,
        item_Wh, item_b, price_Wh, price_b, dept_Wh, dept_b,
        price_mean, price_var, out);
  } else {
    dim3 grid(NB / 8, 3, 1);
    gru_towers<<<grid, 256, 0, stream>>>(
        ids, prices, depts, item_table, price_table, dept_table,
        item_Wx, item_Wh, item_b, price_Wx, price_Wh, price_b,
        dept_Wx, dept_Wh, dept_b, price_mean, price_var, out);
  }
}

// Round 9
// 317.462 us; speedup vs baseline: 3.1386x; 1.0723x over previous
//
#include <hip/hip_runtime.h>

// Problem constants (match reference)
#define ED    32      // embedding / hidden dim
#define SEQ_T 200     // history length
#define NB    4096    // batch
#define H3    96      // 3*ED
#define IV    100001
#define PV    100001
#define DV    1001
#define PV_MAX 100000 // PV-1

#define PIN(x) asm volatile("" : "+v"(x))

typedef __attribute__((ext_vector_type(8))) short bf16x8;   // 8 bf16 (4 VGPRs)
typedef __attribute__((ext_vector_type(4))) float f32x4;    // MFMA acc

__device__ __forceinline__ float rcp_fast(float x) { return __builtin_amdgcn_rcpf(x); }
__device__ __forceinline__ float sigmoid_fast(float x) { return rcp_fast(1.0f + __expf(-x)); }
__device__ __forceinline__ float tanh_fast(float x) {
  const float e = __expf(-2.0f * x);
  return (1.0f - e) * rcp_fast(1.0f + e);
}

// round-to-nearest-even fp32 -> bf16 (as raw short)
__device__ __forceinline__ short bf16_rn(float v) {
  unsigned u = __float_as_uint(v);
  unsigned r = (u + 0x7fffu + ((u >> 16) & 1u)) >> 16;
  return (short)r;
}
__device__ __forceinline__ float bf16_f(short s) {
  return __uint_as_float(((unsigned)(unsigned short)s) << 16);
}

// Broadcast lane K within 32-lane group (swizzle-FMA kernels)
#define BCAST(v, K) \
  __uint_as_float((unsigned)__builtin_amdgcn_ds_swizzle((int)__float_as_uint(v), ((K) << 5)))

#define UNROLL32(M) \
  M(0)  M(1)  M(2)  M(3)  M(4)  M(5)  M(6)  M(7)  \
  M(8)  M(9)  M(10) M(11) M(12) M(13) M(14) M(15) \
  M(16) M(17) M(18) M(19) M(20) M(21) M(22) M(23) \
  M(24) M(25) M(26) M(27) M(28) M(29) M(30) M(31)

template <int TOWER>
__device__ __forceinline__ void fetch_idx(const int* __restrict__ ids,
                                          const float* __restrict__ prices,
                                          const int* __restrict__ depts,
                                          int base, int t, float pmean, float prsq,
                                          int& idx, bool& mk) {
  if constexpr (TOWER == 0) {
    idx = ids[base + t];
    mk = true;
  } else if constexpr (TOWER == 1) {
    const float p = prices[base + t];
    const float pn = (p - pmean) * prsq;
    mk = (pn != 0.0f);
    int q = (int)pn;
    q = q < 0 ? 0 : (q > PV_MAX ? PV_MAX : q);
    idx = q;
  } else {
    const int d = depts[base + t];
    mk = (d != 0);
    idx = d;
  }
}

// ---------------------------------------------------------------------------
// Phase 1 (round-7 proven): fused projection of all three tables.
// XP[v*96 + c], plain hidden order.
// ---------------------------------------------------------------------------
#define NBLK_I ((IV + 255) / 256)
#define NBLK_P ((PV + 255) / 256)
#define NBLK_D ((DV + 255) / 256)

__global__ void __launch_bounds__(256, 2) proj_all(
    const float* __restrict__ item_table, const float* __restrict__ price_table,
    const float* __restrict__ dept_table,
    const float* __restrict__ item_Wx, const float* __restrict__ price_Wx,
    const float* __restrict__ dept_Wx,
    float* __restrict__ itemXP, float* __restrict__ priceXP,
    float* __restrict__ deptXP) {
  int blk = blockIdx.x;
  const float* table; const float* Wx; float* XP; int nrows;
  if (blk < NBLK_I)               { table = item_table;  Wx = item_Wx;  XP = itemXP;  nrows = IV; }
  else if (blk < NBLK_I + NBLK_P) { blk -= NBLK_I;       table = price_table; Wx = price_Wx; XP = priceXP; nrows = PV; }
  else                            { blk -= NBLK_I + NBLK_P; table = dept_table; Wx = dept_Wx; XP = deptXP; nrows = DV; }

  const int j = threadIdx.x & 31;
  const int g = threadIdx.x >> 5;

  float wx0[ED], wx1[ED], wx2[ED];
#pragma unroll
  for (int k = 0; k < ED; ++k) {
    wx0[k] = Wx[k * H3 + j];
    wx1[k] = Wx[k * H3 + 32 + j];
    wx2[k] = Wx[k * H3 + 64 + j];
    PIN(wx0[k]); PIN(wx1[k]); PIN(wx2[k]);
  }

  const int r0 = blk * 256 + g * 32;
  for (int rr = 0; rr < 32; ++rr) {
    const int r = r0 + rr;
    if (r >= nrows) break;
    const float xv = table[(size_t)r * ED + j];
    float a0 = 0.f, a1 = 0.f, a2 = 0.f;
#define PSTEP(K)                              \
    {                                         \
      const float xk = BCAST(xv, K);          \
      a0 = __builtin_fmaf(xk, wx0[K], a0);    \
      a1 = __builtin_fmaf(xk, wx1[K], a1);    \
      a2 = __builtin_fmaf(xk, wx2[K], a2);    \
    }
    UNROLL32(PSTEP)
#undef PSTEP
    float* o = XP + (size_t)r * H3;
    o[j] = a0; o[32 + j] = a1; o[64 + j] = a2;
  }
}

// ---------------------------------------------------------------------------
// Phase 2: MFMA GRU, one wave = 16 batch rows, ONE WAVE PER BLOCK.
// k-PERMUTED operands: for D = A*B, storing both A and B with the same
// permutation pi on the contraction index leaves D unchanged. We pick
//   pi(slot s = quad*8+j) = quad*4 + (j&3) + 16*(j>>2)
// which is exactly the set of hidden indices lane (l15,quad) holds in its
// D-layout hD[2] registers -> the next-step B fragment is built IN-LANE
// (pure bf16 converts), no LDS, no shuffles, no bank conflicts.
// A (weights, loop-invariant) absorbs pi at load time.
// ---------------------------------------------------------------------------
template <int TOWER>
__device__ void tower_mfma(const int* __restrict__ ids,
                           const float* __restrict__ prices,
                           const int* __restrict__ depts,
                           const float* __restrict__ XP,
                           const float* __restrict__ Wh,
                           const float* __restrict__ Bb,
                           float pmean, float prsq,
                           float* __restrict__ out) {
  const int lane = threadIdx.x & 63;
  const int l15  = lane & 15;
  const int quad = lane >> 4;
  const int grp  = blockIdx.x;               // 16-row group (one wave per block)
  const int bRow = grp * 16 + l15;           // this lane's batch row
  const int base = bRow * SEQ_T;

  // Loop-invariant weight A-fragments with pi-permuted k: slot j of lane
  // (l15,quad) holds Wh[pi(quad*8+j)][tile*16 + l15], pi as above.
  bf16x8 wa_hi[6], wa_lo[6];
#pragma unroll
  for (int tile = 0; tile < 6; ++tile) {
#pragma unroll
    for (int j = 0; j < 8; ++j) {
      const int kperm = quad * 4 + (j & 3) + 16 * (j >> 2);
      const float w = Wh[kperm * H3 + tile * 16 + l15];
      const short hi = bf16_rn(w);
      const short lo = bf16_rn(w - bf16_f(hi));
      wa_hi[tile][j] = hi;
      wa_lo[tile][j] = lo;
    }
  }

  // Per-lane bias vectors in D-layout (hidden = tl*16 + quad*4 + reg).
  f32x4 cz[2], cr[2], bi2[2], bh2[2];
#pragma unroll
  for (int tl = 0; tl < 2; ++tl) {
    const int h4 = tl * 16 + quad * 4;
    cz[tl]  = *(const f32x4*)(Bb + h4)      + *(const f32x4*)(Bb + 96 + h4);
    cr[tl]  = *(const f32x4*)(Bb + 32 + h4) + *(const f32x4*)(Bb + 128 + h4);
    bi2[tl] = *(const f32x4*)(Bb + 64 + h4);
    bh2[tl] = *(const f32x4*)(Bb + 160 + h4);
  }

  f32x4 hD[2];   // hD[tl][reg] = h[batch=l15][hid=tl*16+quad*4+reg]
  hD[0] = (f32x4)0.0f; hD[1] = (f32x4)0.0f;

  // Prefetch xp for step 0 (6 float4 gathers in D-layout).
  int idx; bool mk_next;
  fetch_idx<TOWER>(ids, prices, depts, base, 0, pmean, prsq, idx, mk_next);
  f32x4 xq[6];
#pragma unroll
  for (int tile = 0; tile < 6; ++tile)
    xq[tile] = *(const f32x4*)(XP + (size_t)idx * H3 + tile * 16 + quad * 4);

  for (int t = 0; t < SEQ_T; ++t) {
    f32x4 xv[6];
#pragma unroll
    for (int tile = 0; tile < 6; ++tile) xv[tile] = xq[tile];
    const bool mk = mk_next;
    if (t + 1 < SEQ_T) {
      int idn;
      fetch_idx<TOWER>(ids, prices, depts, base, t + 1, pmean, prsq, idn, mk_next);
#pragma unroll
      for (int tile = 0; tile < 6; ++tile)
        xq[tile] = *(const f32x4*)(XP + (size_t)idn * H3 + tile * 16 + quad * 4);
    }

    // --- B fragment built IN-LANE from hD (pi-permuted k) ---
    bf16x8 hh, hl;
#pragma unroll
    for (int j = 0; j < 8; ++j) {
      const float v = hD[j >> 2][j & 3];
      const short hi = bf16_rn(v);
      hh[j] = hi;
      hl[j] = bf16_rn(v - bf16_f(hi));
    }

    // --- MFMA: acc = bias(+xp) + Wh^T @ h^T, split-bf16 (drop lo*lo) ---
    f32x4 acc[6];
    acc[0] = xv[0] + cz[0];  acc[1] = xv[1] + cz[1];
    acc[2] = xv[2] + cr[0];  acc[3] = xv[3] + cr[1];
    acc[4] = bh2[0];         acc[5] = bh2[1];
#pragma unroll
    for (int tile = 0; tile < 6; ++tile) {
      acc[tile] = __builtin_amdgcn_mfma_f32_16x16x32_bf16(wa_hi[tile], hh, acc[tile], 0, 0, 0);
      acc[tile] = __builtin_amdgcn_mfma_f32_16x16x32_bf16(wa_hi[tile], hl, acc[tile], 0, 0, 0);
      acc[tile] = __builtin_amdgcn_mfma_f32_16x16x32_bf16(wa_lo[tile], hh, acc[tile], 0, 0, 0);
    }

    // --- gates (batch = l15, hidden = tl*16+quad*4+reg) ---
#pragma unroll
    for (int tl = 0; tl < 2; ++tl) {
#pragma unroll
      for (int rg = 0; rg < 4; ++rg) {
        const float z  = sigmoid_fast(acc[tl][rg]);
        const float r  = sigmoid_fast(acc[2 + tl][rg]);
        const float g  = tanh_fast(xv[4 + tl][rg] + bi2[tl][rg] + r * acc[4 + tl][rg]);
        const float hn = z * hD[tl][rg] + (1.0f - z) * g;
        hD[tl][rg] = mk ? hn : hD[tl][rg];
      }
    }
  }

  // Output: out[bRow][TOWER*32 + tl*16 + quad*4 + reg]
#pragma unroll
  for (int tl = 0; tl < 2; ++tl)
    *(f32x4*)(out + (size_t)bRow * H3 + TOWER * ED + tl * 16 + quad * 4) = hD[tl];
}

__global__ void __launch_bounds__(64) gru_mfma(
    const int* __restrict__ ids, const float* __restrict__ prices, const int* __restrict__ depts,
    const float* __restrict__ itemXP, const float* __restrict__ priceXP,
    const float* __restrict__ deptXP,
    const float* __restrict__ item_Wh, const float* __restrict__ item_b,
    const float* __restrict__ price_Wh, const float* __restrict__ price_b,
    const float* __restrict__ dept_Wh, const float* __restrict__ dept_b,
    const float* __restrict__ price_mean, const float* __restrict__ price_var,
    float* __restrict__ out) {
  const int tower = blockIdx.y;
  if (tower == 0) {
    tower_mfma<0>(ids, prices, depts, itemXP, item_Wh, item_b, 0.0f, 0.0f, out);
  } else if (tower == 1) {
    const float pm = price_mean[0];
    const float pr = rsqrtf(price_var[0]);
    tower_mfma<1>(ids, prices, depts, priceXP, price_Wh, price_b, pm, pr, out);
  } else {
    tower_mfma<2>(ids, prices, depts, deptXP, dept_Wh, dept_b, 0.0f, 0.0f, out);
  }
}

// ---------------------------------------------------------------------------
// Fallback (ws too small): fused in-loop x@Wx (round-1 structure).
// ---------------------------------------------------------------------------
template <int TOWER>
__device__ void tower_run(const int* __restrict__ ids,
                          const float* __restrict__ prices,
                          const int* __restrict__ depts,
                          const float* __restrict__ table,
                          const float* __restrict__ Wx,
                          const float* __restrict__ Wh,
                          const float* __restrict__ Bb,
                          float pmean, float prsq,
                          float* __restrict__ out) {
  const int j    = threadIdx.x & 31;
  const int b    = blockIdx.x * 8 + (threadIdx.x >> 5);
  const int base = b * SEQ_T;

  float wx0[ED], wx1[ED], wx2[ED], wh0[ED], wh1[ED], wh2[ED];
#pragma unroll
  for (int k = 0; k < ED; ++k) {
    wx0[k] = Wx[k * H3 + j];
    wx1[k] = Wx[k * H3 + 32 + j];
    wx2[k] = Wx[k * H3 + 64 + j];
    wh0[k] = Wh[k * H3 + j];
    wh1[k] = Wh[k * H3 + 32 + j];
    wh2[k] = Wh[k * H3 + 64 + j];
  }
  const float bi0 = Bb[j],      bi1 = Bb[32 + j],  bi2 = Bb[64 + j];
  const float bh0 = Bb[96 + j], bh1 = Bb[128 + j], bh2 = Bb[160 + j];

  float h = 0.0f;
  int idx; bool mk_next;
  fetch_idx<TOWER>(ids, prices, depts, base, 0, pmean, prsq, idx, mk_next);
  float x_next = table[(size_t)idx * ED + j];

  for (int t = 0; t < SEQ_T; ++t) {
    const float xv = x_next;
    const bool  mk = mk_next;
    if (t + 1 < SEQ_T) {
      int idn;
      fetch_idx<TOWER>(ids, prices, depts, base, t + 1, pmean, prsq, idn, mk_next);
      x_next = table[(size_t)idn * ED + j];
    }

    float a0 = bi0, a1 = bi1, a2 = bi2;
    float r0 = bh0, r1 = bh1, r2 = bh2;
#define KSTEP(K)                              \
    {                                         \
      const float xk = BCAST(xv, K);          \
      const float hk = BCAST(h, K);           \
      a0 = __builtin_fmaf(xk, wx0[K], a0);    \
      a1 = __builtin_fmaf(xk, wx1[K], a1);    \
      a2 = __builtin_fmaf(xk, wx2[K], a2);    \
      r0 = __builtin_fmaf(hk, wh0[K], r0);    \
      r1 = __builtin_fmaf(hk, wh1[K], r1);    \
      r2 = __builtin_fmaf(hk, wh2[K], r2);    \
    }
    UNROLL32(KSTEP)
#undef KSTEP

    const float z  = sigmoid_fast(a0 + r0);
    const float r  = sigmoid_fast(a1 + r1);
    const float hc = tanh_fast(a2 + r * r2);
    const float hn = z * h + (1.0f - z) * hc;
    h = mk ? hn : h;
  }
  out[b * H3 + TOWER * ED + j] = h;
}

__global__ void __launch_bounds__(256, 2) gru_towers(
    const int* __restrict__ ids, const float* __restrict__ prices, const int* __restrict__ depts,
    const float* __restrict__ item_table, const float* __restrict__ price_table,
    const float* __restrict__ dept_table,
    const float* __restrict__ item_Wx, const float* __restrict__ item_Wh,
    const float* __restrict__ item_b,
    const float* __restrict__ price_Wx, const float* __restrict__ price_Wh,
    const float* __restrict__ price_b,
    const float* __restrict__ dept_Wx, const float* __restrict__ dept_Wh,
    const float* __restrict__ dept_b,
    const float* __restrict__ price_mean, const float* __restrict__ price_var,
    float* __restrict__ out) {
  const int tower = blockIdx.y;
  if (tower == 0) {
    tower_run<0>(ids, prices, depts, item_table, item_Wx, item_Wh, item_b, 0.0f, 0.0f, out);
  } else if (tower == 1) {
    const float pm = price_mean[0];
    const float pr = rsqrtf(price_var[0]);
    tower_run<1>(ids, prices, depts, price_table, price_Wx, price_Wh, price_b, pm, pr, out);
  } else {
    tower_run<2>(ids, prices, depts, dept_table, dept_Wx, dept_Wh, dept_b, 0.0f, 0.0f, out);
  }
}

extern "C" void kernel_launch(void* const* d_in, const int* in_sizes, int n_in,
                              void* d_out, int out_size, void* d_ws, size_t ws_size,
                              hipStream_t stream) {
  const int*   ids         = (const int*)d_in[0];
  const float* prices      = (const float*)d_in[1];
  const int*   depts       = (const int*)d_in[2];
  const float* item_table  = (const float*)d_in[3];
  const float* price_table = (const float*)d_in[4];
  const float* dept_table  = (const float*)d_in[5];
  const float* item_Wx     = (const float*)d_in[6];
  const float* item_Wh     = (const float*)d_in[7];
  const float* item_b      = (const float*)d_in[8];
  const float* price_Wx    = (const float*)d_in[9];
  const float* price_Wh    = (const float*)d_in[10];
  const float* price_b     = (const float*)d_in[11];
  const float* dept_Wx     = (const float*)d_in[12];
  const float* dept_Wh     = (const float*)d_in[13];
  const float* dept_b      = (const float*)d_in[14];
  const float* price_mean  = (const float*)d_in[15];
  const float* price_var   = (const float*)d_in[16];
  float* out = (float*)d_out;

  const size_t need = (size_t)(IV + PV + DV) * H3 * sizeof(float);
  if (ws_size >= need) {
    float* itemXP  = (float*)d_ws;
    float* priceXP = itemXP + (size_t)IV * H3;
    float* deptXP  = priceXP + (size_t)PV * H3;

    proj_all<<<dim3(NBLK_I + NBLK_P + NBLK_D), 256, 0, stream>>>(
        item_table, price_table, dept_table,
        item_Wx, price_Wx, dept_Wx,
        itemXP, priceXP, deptXP);

    dim3 grid(NB / 16, 3, 1);   // one wave per block -> spreads over all CUs
    gru_mfma<<<grid, 64, 0, stream>>>(
        ids, prices, depts, itemXP, priceXP, deptXP,
        item_Wh, item_b, price_Wh, price_b, dept_Wh, dept_b,
        price_mean, price_var, out);
  } else {
    dim3 grid(NB / 8, 3, 1);
    gru_towers<<<grid, 256, 0, stream>>>(
        ids, prices, depts, item_table, price_table, dept_table,
        item_Wx, item_Wh, item_b, price_Wx, price_Wh, price_b,
        dept_Wx, dept_Wh, dept_b, price_mean, price_var, out);
  }
}